// Round 12
// baseline (195.931 us; speedup 1.0000x reference)
//
#include <hip/hip_runtime.h>
#include <hip/hip_bf16.h>

// Problem constants
#define B_   2
#define N_   2048
#define D_   128
#define H_   16
#define ALL_ 2048
#define M_   (B_*N_)    // 4096 total rows
#define BH_  (B_*H_)    // 32 (batch*heads)

typedef __bf16 bf16;
typedef __bf16 bf16x8 __attribute__((ext_vector_type(8)));
typedef __bf16 bf16x4 __attribute__((ext_vector_type(4)));
typedef float  floatx4 __attribute__((ext_vector_type(4)));

#define MFMA32K(a,b,c) __builtin_amdgcn_mfma_f32_16x16x32_bf16((a),(b),(c),0,0,0)

// async global->LDS DMA, 16B per lane (m97 pattern)
__device__ inline void load_lds16(const bf16* g, bf16* l) {
    __builtin_amdgcn_global_load_lds((const __attribute__((address_space(1))) void*)g,
                                     (__attribute__((address_space(3))) void*)l, 16, 0, 0);
}

// s_waitcnt imm encoding (gfx9/CDNA): vmcnt[3:0]=bits3:0, expcnt=bits6:4,
// lgkmcnt=bits11:8. No-wait fields = all-ones.
#define WAITCNT_VM(n) ((0xF << 8) | (0x7 << 4) | (n))

// ---------------------------------------------------------------------------
// FRAGMENT-MAJOR LAYOUTS (all global tensors MFMA-fragment-major so every
// global access in every kernel is lane*16B contiguous):
//  A/B-frag convention (16x16x32): elem j of lane (lrow=lane&15,quad=lane>>4)
//    A[m=lrow][k=kf*32+quad*8+j]  /  B[k=kf*32+quad*8+j][n=lrow]
//  Wf  (Wq/Wk/Wv): [ct=col/16 (128)][kf (4)][lane][8]   col=ct*16+lrow
//  Wof:            [ct (8)][kf (64)][lane][8]
//  xf:             [rt=row/16 (256)][kf (4)][lane][8]
//  Qf/Kf:          [bh][t=q/16 (128)][kf (4)][lane][8]
//  Vf:             [bh][kb (32)][nf (8)][g (2)][lane][8]
//        elem j = V[key=kb*64+(2g+(j>>2))*16+quad*4+(j&3)][d=nf*16+lrow]
//  ctxf:           [qt (256)][kf (64)][lane][8]
// ---------------------------------------------------------------------------

// ---------------------------------------------------------------------------
// Kernel T: prep. Converts weights + x to fragment-major bf16 via LDS tiles;
// mask -> float bias. Blocks: 0..95 Wq/Wk/Wv, 96..111 Wo, 112..175 xf,
// 176..191 mbias.
// ---------------------------------------------------------------------------
__global__ __launch_bounds__(256) void prep_weights(const float* __restrict__ x,
                                                    const float* __restrict__ Wq,
                                                    const float* __restrict__ Wk,
                                                    const float* __restrict__ Wv,
                                                    const float* __restrict__ Wo,
                                                    const int* __restrict__ mask,
                                                    bf16* __restrict__ Wqf,
                                                    bf16* __restrict__ Wkf,
                                                    bf16* __restrict__ Wvf,
                                                    bf16* __restrict__ Wof,
                                                    bf16* __restrict__ xf,
                                                    float* __restrict__ mbias) {
    __shared__ bf16 pw[16896];
    int bid = blockIdx.x, t = threadIdx.x;
    int lane = t & 63, wave = t >> 6;
    int lrow = lane & 15, quad = lane >> 4;

    if (bid < 96) {
        // ---- Wq/Wk/Wv [128][2048] -> Wf frags, 64 cols per block ----
        int m = bid >> 5, cg = bid & 31;         // col-group: cols cg*64..+63
        const float* W = (m == 0) ? Wq : (m == 1) ? Wk : Wv;
        bf16* Wf       = (m == 0) ? Wqf : (m == 1) ? Wkf : Wvf;
        int slot = t & 15, rowb = t >> 4;        // 16 col4-slots, 16 row-slots
#pragma unroll
        for (int i = 0; i < 8; i++) {
            int r = rowb + i * 16;
            float4 v = *(const float4*)(W + (size_t)r * 2048 + cg * 64 + slot * 4);
            bf16x4 o; o[0]=(bf16)v.x; o[1]=(bf16)v.y; o[2]=(bf16)v.z; o[3]=(bf16)v.w;
            *(bf16x4*)(&pw[r * 68 + slot * 4]) = o;   // tile [k 128][col 64] stride 68
        }
        __syncthreads();
        int ctl = wave;                          // local col-tile 0..3
#pragma unroll
        for (int kf = 0; kf < 4; kf++) {
            bf16x8 w;
#pragma unroll
            for (int j = 0; j < 8; j++) w[j] = pw[(kf * 32 + quad * 8 + j) * 68 + ctl * 16 + lrow];
            *(bf16x8*)(Wf + (size_t)((cg * 4 + ctl) * 4 + kf) * 512 + lane * 8) = w;
        }
    } else if (bid < 112) {
        // ---- Wo [2048][128] -> Wof frags, 128 k-rows per block ----
        int kb16 = bid - 96, k0 = kb16 * 128;
        int slot = t & 31, rowb = t >> 5;
#pragma unroll
        for (int i = 0; i < 16; i++) {
            int r = rowb + i * 8;
            float4 v = *(const float4*)(Wo + (size_t)(k0 + r) * 128 + slot * 4);
            bf16x4 o; o[0]=(bf16)v.x; o[1]=(bf16)v.y; o[2]=(bf16)v.z; o[3]=(bf16)v.w;
            *(bf16x4*)(&pw[r * 132 + slot * 4]) = o;  // tile [k 128][col 128] stride 132
        }
        __syncthreads();
        int kfl = wave;                          // local kf 0..3 -> kf = kb16*4+kfl
#pragma unroll
        for (int ct = 0; ct < 8; ct++) {
            bf16x8 w;
#pragma unroll
            for (int j = 0; j < 8; j++) w[j] = pw[(kfl * 32 + quad * 8 + j) * 132 + ct * 16 + lrow];
            *(bf16x8*)(Wof + (size_t)(ct * 64 + kb16 * 4 + kfl) * 512 + lane * 8) = w;
        }
    } else if (bid < 176) {
        // ---- x [4096][128] fp32 -> xf frags (A-layout), 64 rows per block ----
        int rg = bid - 112, r0 = rg * 64;
        int slot = t & 31, rowb = t >> 5;
#pragma unroll
        for (int i = 0; i < 8; i++) {
            int r = rowb + i * 8;
            float4 v = *(const float4*)(x + (size_t)(r0 + r) * 128 + slot * 4);
            bf16x4 o; o[0]=(bf16)v.x; o[1]=(bf16)v.y; o[2]=(bf16)v.z; o[3]=(bf16)v.w;
            *(bf16x4*)(&pw[r * 136 + slot * 4]) = o;  // tile [row 64][col 128] stride 136
        }
        __syncthreads();
        int rtl = wave;                          // local row-tile 0..3
#pragma unroll
        for (int kf = 0; kf < 4; kf++) {
            bf16x8 w = *(const bf16x8*)(&pw[(rtl * 16 + lrow) * 136 + kf * 32 + quad * 8]);
            *(bf16x8*)(xf + (size_t)((rg * 4 + rtl) * 4 + kf) * 512 + lane * 8) = w;
        }
    } else {
        int e = (bid - 176) * 256 + t;
        mbias[e] = mask[e] ? 0.0f : -30.0f;
    }
}

// ---------------------------------------------------------------------------
// Kernel A: Q/K/V projection, z SPLIT ACROSS BLOCKS (grid (64,32,3), 6144
// blocks = 24/CU): removes the 3-phase barrier serialization of the fused
// version and triples TLP. xf re-read 3x (+4MB L2 — trivial). All frag
// accesses coalesced; outputs Qf/Kf/Vf fragment-major.
// ---------------------------------------------------------------------------
__global__ __launch_bounds__(256) void qkv_proj(const bf16* __restrict__ xf,
                                                const float* __restrict__ bq,
                                                const float* __restrict__ bk,
                                                const float* __restrict__ bv,
                                                const bf16* __restrict__ Wqf,
                                                const bf16* __restrict__ Wkf,
                                                const bf16* __restrict__ Wvf,
                                                bf16* __restrict__ Qf,
                                                bf16* __restrict__ Kf,
                                                bf16* __restrict__ Vf) {
    __shared__ bf16 tile[64][72];

    int z = blockIdx.z;
    const float* bias = (z == 0) ? bq : (z == 1) ? bk : bv;
    const bf16*  Wf   = (z == 0) ? Wqf : (z == 1) ? Wkf : Wvf;

    int tid = threadIdx.x;
    int wave = tid >> 6, lane = tid & 63;
    int lrow = lane & 15, quad = lane >> 4;
    int r0b = blockIdx.x * 64;                // rows (b*N+n)
    int c0 = blockIdx.y * 64;                 // cols (h*128+dim)
    int cg4 = c0 >> 4;                        // global col-tile base

    // A-frags for this wave's 16-row tile, from xf (coalesced)
    int rt = (r0b >> 4) + wave;
    bf16x8 a[4];
#pragma unroll
    for (int kf = 0; kf < 4; kf++)
        a[kf] = *(const bf16x8*)(xf + (size_t)(rt * 4 + kf) * 512 + lane * 8);

    int bb = r0b >> 11;            // batch
    int h  = c0 >> 7;              // head
    int bhw = bb * 16 + h;
    int tile16 = (r0b & 2047) >> 4;   // 16-row tile index within bh
    int kbt = (r0b & 2047) >> 6;      // 64-key tile index (for Vf)
    floatx4 zero4 = {0.f, 0.f, 0.f, 0.f};

    floatx4 acc[4] = {zero4, zero4, zero4, zero4};
#pragma unroll
    for (int kf = 0; kf < 4; kf++) {
#pragma unroll
        for (int nf = 0; nf < 4; nf++) {
            bf16x8 b = *(const bf16x8*)(Wf + (size_t)((cg4 + nf) * 4 + kf) * 512 + lane * 8);
            acc[nf] = MFMA32K(a[kf], b, acc[nf]);
        }
    }

    // stage (+bias, cast). z<2: [row][col]; z==2: [col][row]
#pragma unroll
    for (int nf = 0; nf < 4; nf++) {
        int col = nf * 16 + lrow;
        float bvv = bias[c0 + col];
#pragma unroll
        for (int r = 0; r < 4; r++) {
            int row = wave * 16 + quad * 4 + r;
            bf16 val = (bf16)(acc[nf][r] + bvv);
            if (z < 2) tile[row][col] = val;
            else       tile[col][row] = val;
        }
    }
    __syncthreads();

    if (z < 2) {
        // Q and K share the same fragment-major layout
        bf16* dst = (z == 0) ? Qf : Kf;
        int s = wave;                              // 16-row tile 0..3
        int kfbase = (c0 & 127) >> 5;              // 0 or 2
        size_t fbase = ((size_t)bhw * 128 + tile16 + s) * 4 + kfbase;
#pragma unroll
        for (int kfl = 0; kfl < 2; kfl++) {
            bf16x8 w = *(const bf16x8*)(&tile[s * 16 + lrow][kfl * 32 + quad * 8]);
            *(bf16x8*)(dst + (fbase + kfl) * 512 + lane * 8) = w;
        }
    } else {
        int nfl = wave;
        int nfbase = (c0 & 127) >> 4;              // 0 or 4
        size_t fbase = (((size_t)bhw * 32 + kbt) * 8 + (nfbase + nfl)) * 2;
#pragma unroll
        for (int g = 0; g < 2; g++) {
            bf16x4 a0 = *(const bf16x4*)(&tile[nfl * 16 + lrow][g * 32 + quad * 4]);
            bf16x4 a1 = *(const bf16x4*)(&tile[nfl * 16 + lrow][g * 32 + 16 + quad * 4]);
            bf16x8 w;
            w[0]=a0[0]; w[1]=a0[1]; w[2]=a0[2]; w[3]=a0[3];
            w[4]=a1[0]; w[5]=a1[1]; w[6]=a1[2]; w[7]=a1[3];
            *(bf16x8*)(Vf + (fbase + g) * 512 + lane * 8) = w;
        }
    }
}

// ---------------------------------------------------------------------------
// Kernel B: flash attention — FROZEN at the R11 structure (best of R4-R11):
// 4 waves/block, u=2, 128 q/block, 512 blocks, XCD swizzle, frag-major
// in/out, K+V LDS double-buffer, single barrier/iter, ones-MFMA l-accum.
// ---------------------------------------------------------------------------
__global__ __launch_bounds__(256) void flash_attn(const bf16* __restrict__ Qf,
                                                  const bf16* __restrict__ Kf,
                                                  const bf16* __restrict__ Vf,
                                                  const float* __restrict__ mbias,
                                                  const int* __restrict__ mask,
                                                  bf16* __restrict__ ctxf) {
    __shared__ bf16 sm[32768];   // [buf 0/1][K 8192 | V 8192]; epilogue reuses [0,17408)

    int tid = threadIdx.x;
    int wave = tid >> 6, lane = tid & 63;
    int lrow = lane & 15, quad = lane >> 4;
    // XCD swizzle: 512 blocks = 8 xcd * (4 bh * 16 qblk)
    int bid = blockIdx.x;
    int xcd = bid & 7, seq = bid >> 3;          // seq 0..63
    int bh  = xcd * 4 + (seq >> 4);             // 0..31
    int qblk = seq & 15;                        // 0..15
    int b  = bh >> 4;
    int q0 = qblk * 128 + wave * 32;

    const float* mbp = mbias + b * N_;
    const bf16* kbase = Kf + (size_t)bh * 32 * 8192;
    const bf16* vbase = Vf + (size_t)bh * 32 * 8192;

    // Q B-frags from Qf (coalesced 16B loads), held all loop
    bf16x8 qf[2][4];
#pragma unroll
    for (int u = 0; u < 2; u++)
#pragma unroll
        for (int kf = 0; kf < 4; kf++)
            qf[u][kf] = *(const bf16x8*)(Qf + (size_t)(((size_t)bh * 128 + (q0 >> 4) + u) * 4 + kf) * 512 + lane * 8);

    bf16x8 ones;
#pragma unroll
    for (int j = 0; j < 8; j++) ones[j] = (bf16)1.0f;

    floatx4 zero4 = {0.f, 0.f, 0.f, 0.f};
    floatx4 O[2][8];
#pragma unroll
    for (int u = 0; u < 2; u++)
#pragma unroll
        for (int nf = 0; nf < 8; nf++) O[u][nf] = zero4;
    floatx4 Oext[2] = {zero4, zero4};   // row sums l[q] via ones-MFMA

    const float scale = 0.0883883476483184f;   // 1/sqrt(128)

    // ---- prologue: DMA tile 0 into buffer 0 (8 loads/wave) ----
#pragma unroll
    for (int i = 0; i < 4; i++) {
        int seg = wave * 4 + i;                // 0..15, 1KB each
        load_lds16(kbase + seg * 512 + lane * 8, &sm[seg * 512]);
        load_lds16(vbase + seg * 512 + lane * 8, &sm[8192 + seg * 512]);
    }

    for (int kb = 0; kb < 32; kb++) {
        int cur = (kb & 1) << 14;              // 0 or 16384

        // ---- 1./2. wait my DMA(kb), then block-wide visibility ----
        __builtin_amdgcn_s_waitcnt(WAITCNT_VM(0));
        __builtin_amdgcn_s_barrier();

        // ---- 3. prefetch DMA(kb+1) into the other buffer ----
        if (kb < 31) {
            int nxt = cur ^ 16384;
            const bf16* ksrc = kbase + (size_t)(kb + 1) * 8192;
            const bf16* vsrc = vbase + (size_t)(kb + 1) * 8192;
#pragma unroll
            for (int i = 0; i < 4; i++) {
                int seg = wave * 4 + i;
                load_lds16(ksrc + seg * 512 + lane * 8, &sm[nxt + seg * 512]);
                load_lds16(vsrc + seg * 512 + lane * 8, &sm[nxt + 8192 + seg * 512]);
            }
        }

        // ---- 4. S^T per 16-key tile; exp; pack into K=32 B-frags ----
        bf16x8 pf[2][2];
#pragma unroll
        for (int s = 0; s < 4; s++) {
            floatx4 S0 = zero4, S1 = zero4;
#pragma unroll
            for (int kf = 0; kf < 4; kf++) {
                bf16x8 kfr = *(const bf16x8*)(&sm[cur + ((s * 4 + kf) * 64 + lane) * 8]);
                S0 = MFMA32K(kfr, qf[0][kf], S0);
                S1 = MFMA32K(kfr, qf[1][kf], S1);
            }
            float4 mb4 = *(const float4*)(mbp + kb * 64 + s * 16 + quad * 4);
            const float* mbr = (const float*)&mb4;
            int g = s >> 1, o = (s & 1) * 4;
#pragma unroll
            for (int r = 0; r < 4; r++) {
                float p0 = __expf(fmaf(S0[r], scale, mbr[r]));
                float p1 = __expf(fmaf(S1[r], scale, mbr[r]));
                pf[0][g][o + r] = (bf16)p0;
                pf[1][g][o + r] = (bf16)p1;
            }
        }

        // ---- l row-sums via ones-MFMA ----
#pragma unroll
        for (int g = 0; g < 2; g++) {
            Oext[0] = MFMA32K(ones, pf[0][g], Oext[0]);
            Oext[1] = MFMA32K(ones, pf[1][g], Oext[1]);
        }

        // ---- PV: O^T[d][q] += V^T P, full-rate K=32 ----
#pragma unroll
        for (int nf = 0; nf < 8; nf++) {
#pragma unroll
            for (int g = 0; g < 2; g++) {
                bf16x8 vfr = *(const bf16x8*)(&sm[cur + 8192 + ((nf * 2 + g) * 64 + lane) * 8]);
                O[0][nf] = MFMA32K(vfr, pf[0][g], O[0][nf]);
                O[1][nf] = MFMA32K(vfr, pf[1][g], O[1][nf]);
            }
        }
        // no end-of-iter barrier: next iter's barrier (after vmcnt) protects
        // buf[nxt] — every wave reaching it has finished this iter's reads
    }

    // ---- epilogue: normalize, query-mask, reshape via LDS -> ctxf frags ----
    __syncthreads();                    // full drain before reusing sm
    const int* mp = mask + b * N_;
    int wb = wave * 4352;               // 32 rows * 136 stride per wave
#pragma unroll
    for (int u = 0; u < 2; u++) {
        float lsum = Oext[u][0];
        int q = q0 + u * 16 + lrow;
        float rl = (mp[q] && lsum > 0.f) ? (1.0f / lsum) : 0.f;
#pragma unroll
        for (int nf = 0; nf < 8; nf++) {
            bf16x4 o;
#pragma unroll
            for (int j = 0; j < 4; j++) o[j] = (bf16)(O[u][nf][j] * rl);
            *(bf16x4*)(&sm[wb + (u * 16 + lrow) * 136 + nf * 16 + quad * 4]) = o;
        }
    }
    __syncthreads();
    int h4 = (bh & 15) * 4;
    size_t qtb = (size_t)b * 128 + (q0 >> 4);
#pragma unroll
    for (int u = 0; u < 2; u++) {
#pragma unroll
        for (int kfl = 0; kfl < 4; kfl++) {
            bf16x8 w = *(const bf16x8*)(&sm[wb + (u * 16 + lrow) * 136 + kfl * 32 + quad * 8]);
            *(bf16x8*)(ctxf + ((qtb + u) * 64 + h4 + kfl) * 512 + lane * 8) = w;
        }
    }
}

// ---------------------------------------------------------------------------
// Kernel C: out = ctx @ Wo + bo, fp32 out. SPLIT-K x2: 2 waves/block, wave w
// accumulates kf-half w, LDS-combine, wave 0 stores. 2048 waves = 8/CU
// (was 4/CU with one-wave blocks — latency-naked). Deterministic.
// ---------------------------------------------------------------------------
__global__ __launch_bounds__(128) void out_proj(const bf16* __restrict__ ctxf,
                                                const bf16* __restrict__ Wof,
                                                const float* __restrict__ bo,
                                                float* __restrict__ out) {
    __shared__ float red[512];         // wave1 partials: [nf2][r4][lane64]
    int tid = threadIdx.x;
    int wave = tid >> 6, lane = tid & 63;
    int lrow = lane & 15, quad = lane >> 4;
    int qt = blockIdx.x;               // 16-row tile
    int ct = blockIdx.y * 2;           // two 16-col tiles
    int r0 = qt * 16, c0 = ct * 16;

    floatx4 zero4 = {0.f, 0.f, 0.f, 0.f};
    floatx4 acc[2] = {zero4, zero4};
    const bf16* ap = ctxf + ((size_t)qt * 64 + wave * 32) * 512 + lane * 8;
    const bf16* b0 = Wof + ((size_t)ct * 64 + wave * 32) * 512 + lane * 8;
    const bf16* b1 = b0 + (size_t)64 * 512;
#pragma unroll 4
    for (int kf = 0; kf < 32; kf++) {
        bf16x8 a  = *(const bf16x8*)(ap + (size_t)kf * 512);
        bf16x8 w0 = *(const bf16x8*)(b0 + (size_t)kf * 512);
        bf16x8 w1 = *(const bf16x8*)(b1 + (size_t)kf * 512);
        acc[0] = MFMA32K(a, w0, acc[0]);
        acc[1] = MFMA32K(a, w1, acc[1]);
    }
    if (wave == 1) {
#pragma unroll
        for (int nf = 0; nf < 2; nf++)
#pragma unroll
            for (int r = 0; r < 4; r++)
                red[nf * 256 + r * 64 + lane] = acc[nf][r];
    }
    __syncthreads();
    if (wave == 0) {
#pragma unroll
        for (int nf = 0; nf < 2; nf++) {
            int col = c0 + nf * 16 + lrow;
            float bv = bo[col];
#pragma unroll
            for (int r = 0; r < 4; r++) {
                int m = r0 + quad * 4 + r;
                out[(size_t)m * 128 + col] = acc[nf][r] + red[nf * 256 + r * 64 + lane] + bv;
            }
        }
    }
}

// ---------------------------------------------------------------------------
extern "C" void kernel_launch(void* const* d_in, const int* in_sizes, int n_in,
                              void* d_out, int out_size, void* d_ws, size_t ws_size,
                              hipStream_t stream) {
    const float* x    = (const float*)d_in[0];
    const int*   mask = (const int*)d_in[1];
    const float* Wq   = (const float*)d_in[2];
    const float* bq   = (const float*)d_in[3];
    const float* Wk   = (const float*)d_in[4];
    const float* bk   = (const float*)d_in[5];
    const float* Wv   = (const float*)d_in[6];
    const float* bv   = (const float*)d_in[7];
    const float* Wo   = (const float*)d_in[8];
    const float* bo   = (const float*)d_in[9];
    float* out = (float*)d_out;

    char* ws = (char*)d_ws;
    size_t off = 0;
    bf16* Wqf = (bf16*)(ws + off); off += (size_t)262144 * 2;
    bf16* Wkf = (bf16*)(ws + off); off += (size_t)262144 * 2;
    bf16* Wvf = (bf16*)(ws + off); off += (size_t)262144 * 2;
    bf16* Wof = (bf16*)(ws + off); off += (size_t)262144 * 2;
    bf16* xf  = (bf16*)(ws + off); off += (size_t)524288 * 2;
    size_t qkv_elems = (size_t)BH_ * N_ * 128;           // 8.4M
    bf16* Qf  = (bf16*)(ws + off); off += qkv_elems * 2; // fragment-major
    bf16* Kf  = (bf16*)(ws + off); off += qkv_elems * 2; // fragment-major
    bf16* Vf  = (bf16*)(ws + off); off += qkv_elems * 2; // fragment-major
    bf16* ctxf = (bf16*)(ws + off); off += (size_t)M_ * ALL_ * 2;
    float* mbias = (float*)(ws + off); off += (size_t)B_ * N_ * 4;
    (void)ws_size; (void)in_sizes; (void)n_in; (void)out_size;

    prep_weights<<<192, 256, 0, stream>>>(x, Wq, Wk, Wv, Wo, mask,
                                          Wqf, Wkf, Wvf, Wof, xf, mbias);

    qkv_proj<<<dim3(64, 32, 3), 256, 0, stream>>>(xf, bq, bk, bv, Wqf, Wkf, Wvf,
                                                  Qf, Kf, Vf);

    flash_attn<<<512, 256, 0, stream>>>(Qf, Kf, Vf, mbias, mask, ctxf);

    out_proj<<<dim3(256, 4), 128, 0, stream>>>(ctxf, Wof, bo, out);
}

// Round 14
// 184.099 us; speedup vs baseline: 1.0643x; 1.0643x over previous
//
#include <hip/hip_runtime.h>
#include <hip/hip_bf16.h>

// Problem constants
#define B_   2
#define N_   2048
#define D_   128
#define H_   16
#define ALL_ 2048
#define M_   (B_*N_)    // 4096 total rows
#define BH_  (B_*H_)    // 32 (batch*heads)

typedef __bf16 bf16;
typedef __bf16 bf16x8 __attribute__((ext_vector_type(8)));
typedef __bf16 bf16x4 __attribute__((ext_vector_type(4)));
typedef float  floatx4 __attribute__((ext_vector_type(4)));

#define MFMA32K(a,b,c) __builtin_amdgcn_mfma_f32_16x16x32_bf16((a),(b),(c),0,0,0)

// async global->LDS DMA, 16B per lane (m97 pattern).
// NOTE: global address is PER-LANE (pass base + lane*8 bf16 elems);
// LDS address is wave-uniform base (HW adds lane*16).
__device__ inline void load_lds16(const bf16* g, bf16* l) {
    __builtin_amdgcn_global_load_lds((const __attribute__((address_space(1))) void*)g,
                                     (__attribute__((address_space(3))) void*)l, 16, 0, 0);
}

// s_waitcnt imm encoding (gfx9/CDNA): vmcnt[3:0]=bits3:0, expcnt=bits6:4,
// lgkmcnt=bits11:8. No-wait fields = all-ones.
#define WAITCNT_VM(n) ((0xF << 8) | (0x7 << 4) | (n))

// ---------------------------------------------------------------------------
// FRAGMENT-MAJOR LAYOUTS (all global tensors MFMA-fragment-major so every
// global access in every kernel is lane*16B contiguous):
//  A/B-frag convention (16x16x32): elem j of lane (lrow=lane&15,quad=lane>>4)
//    A[m=lrow][k=kf*32+quad*8+j]  /  B[k=kf*32+quad*8+j][n=lrow]
//  Wf  (Wq/Wk/Wv): [ct=col/16 (128)][kf (4)][lane][8]   col=ct*16+lrow
//  Wof:            [ct (8)][kf (64)][lane][8]
//  xf:             [rt=row/16 (256)][kf (4)][lane][8]
//  Qf/Kf:          [bh][t=q/16 (128)][kf (4)][lane][8]
//  Vf:             [bh][kb (32)][nf (8)][g (2)][lane][8]
//        elem j = V[key=kb*64+(2g+(j>>2))*16+quad*4+(j&3)][d=nf*16+lrow]
//  ctxf:           [qt (256)][kf (64)][lane][8]
// ---------------------------------------------------------------------------

// ---------------------------------------------------------------------------
// Kernel T: prep. Converts weights + x to fragment-major bf16 via LDS tiles;
// mask -> float bias. Blocks: 0..95 Wq/Wk/Wv, 96..111 Wo, 112..175 xf,
// 176..191 mbias.
// ---------------------------------------------------------------------------
__global__ __launch_bounds__(256) void prep_weights(const float* __restrict__ x,
                                                    const float* __restrict__ Wq,
                                                    const float* __restrict__ Wk,
                                                    const float* __restrict__ Wv,
                                                    const float* __restrict__ Wo,
                                                    const int* __restrict__ mask,
                                                    bf16* __restrict__ Wqf,
                                                    bf16* __restrict__ Wkf,
                                                    bf16* __restrict__ Wvf,
                                                    bf16* __restrict__ Wof,
                                                    bf16* __restrict__ xf,
                                                    float* __restrict__ mbias) {
    __shared__ bf16 pw[16896];
    int bid = blockIdx.x, t = threadIdx.x;
    int lane = t & 63, wave = t >> 6;
    int lrow = lane & 15, quad = lane >> 4;

    if (bid < 96) {
        // ---- Wq/Wk/Wv [128][2048] -> Wf frags, 64 cols per block ----
        int m = bid >> 5, cg = bid & 31;         // col-group: cols cg*64..+63
        const float* W = (m == 0) ? Wq : (m == 1) ? Wk : Wv;
        bf16* Wf       = (m == 0) ? Wqf : (m == 1) ? Wkf : Wvf;
        int slot = t & 15, rowb = t >> 4;        // 16 col4-slots, 16 row-slots
#pragma unroll
        for (int i = 0; i < 8; i++) {
            int r = rowb + i * 16;
            float4 v = *(const float4*)(W + (size_t)r * 2048 + cg * 64 + slot * 4);
            bf16x4 o; o[0]=(bf16)v.x; o[1]=(bf16)v.y; o[2]=(bf16)v.z; o[3]=(bf16)v.w;
            *(bf16x4*)(&pw[r * 68 + slot * 4]) = o;   // tile [k 128][col 64] stride 68
        }
        __syncthreads();
        int ctl = wave;                          // local col-tile 0..3
#pragma unroll
        for (int kf = 0; kf < 4; kf++) {
            bf16x8 w;
#pragma unroll
            for (int j = 0; j < 8; j++) w[j] = pw[(kf * 32 + quad * 8 + j) * 68 + ctl * 16 + lrow];
            *(bf16x8*)(Wf + (size_t)((cg * 4 + ctl) * 4 + kf) * 512 + lane * 8) = w;
        }
    } else if (bid < 112) {
        // ---- Wo [2048][128] -> Wof frags, 128 k-rows per block ----
        int kb16 = bid - 96, k0 = kb16 * 128;
        int slot = t & 31, rowb = t >> 5;
#pragma unroll
        for (int i = 0; i < 16; i++) {
            int r = rowb + i * 8;
            float4 v = *(const float4*)(Wo + (size_t)(k0 + r) * 128 + slot * 4);
            bf16x4 o; o[0]=(bf16)v.x; o[1]=(bf16)v.y; o[2]=(bf16)v.z; o[3]=(bf16)v.w;
            *(bf16x4*)(&pw[r * 132 + slot * 4]) = o;  // tile [k 128][col 128] stride 132
        }
        __syncthreads();
        int kfl = wave;                          // local kf 0..3 -> kf = kb16*4+kfl
#pragma unroll
        for (int ct = 0; ct < 8; ct++) {
            bf16x8 w;
#pragma unroll
            for (int j = 0; j < 8; j++) w[j] = pw[(kfl * 32 + quad * 8 + j) * 132 + ct * 16 + lrow];
            *(bf16x8*)(Wof + (size_t)(ct * 64 + kb16 * 4 + kfl) * 512 + lane * 8) = w;
        }
    } else if (bid < 176) {
        // ---- x [4096][128] fp32 -> xf frags (A-layout), 64 rows per block ----
        int rg = bid - 112, r0 = rg * 64;
        int slot = t & 31, rowb = t >> 5;
#pragma unroll
        for (int i = 0; i < 8; i++) {
            int r = rowb + i * 8;
            float4 v = *(const float4*)(x + (size_t)(r0 + r) * 128 + slot * 4);
            bf16x4 o; o[0]=(bf16)v.x; o[1]=(bf16)v.y; o[2]=(bf16)v.z; o[3]=(bf16)v.w;
            *(bf16x4*)(&pw[r * 136 + slot * 4]) = o;  // tile [row 64][col 128] stride 136
        }
        __syncthreads();
        int rtl = wave;                          // local row-tile 0..3
#pragma unroll
        for (int kf = 0; kf < 4; kf++) {
            bf16x8 w = *(const bf16x8*)(&pw[(rtl * 16 + lrow) * 136 + kf * 32 + quad * 8]);
            *(bf16x8*)(xf + (size_t)((rg * 4 + rtl) * 4 + kf) * 512 + lane * 8) = w;
        }
    } else {
        int e = (bid - 176) * 256 + t;
        mbias[e] = mask[e] ? 0.0f : -30.0f;
    }
}

// ---------------------------------------------------------------------------
// Kernel A: Q/K/V projection, z split across blocks (grid (64,32,3)).
// All frag accesses coalesced; outputs Qf/Kf/Vf fragment-major.
// ---------------------------------------------------------------------------
__global__ __launch_bounds__(256) void qkv_proj(const bf16* __restrict__ xf,
                                                const float* __restrict__ bq,
                                                const float* __restrict__ bk,
                                                const float* __restrict__ bv,
                                                const bf16* __restrict__ Wqf,
                                                const bf16* __restrict__ Wkf,
                                                const bf16* __restrict__ Wvf,
                                                bf16* __restrict__ Qf,
                                                bf16* __restrict__ Kf,
                                                bf16* __restrict__ Vf) {
    __shared__ bf16 tile[64][72];

    int z = blockIdx.z;
    const float* bias = (z == 0) ? bq : (z == 1) ? bk : bv;
    const bf16*  Wf   = (z == 0) ? Wqf : (z == 1) ? Wkf : Wvf;

    int tid = threadIdx.x;
    int wave = tid >> 6, lane = tid & 63;
    int lrow = lane & 15, quad = lane >> 4;
    int r0b = blockIdx.x * 64;                // rows (b*N+n)
    int c0 = blockIdx.y * 64;                 // cols (h*128+dim)
    int cg4 = c0 >> 4;                        // global col-tile base

    // A-frags for this wave's 16-row tile, from xf (coalesced)
    int rt = (r0b >> 4) + wave;
    bf16x8 a[4];
#pragma unroll
    for (int kf = 0; kf < 4; kf++)
        a[kf] = *(const bf16x8*)(xf + (size_t)(rt * 4 + kf) * 512 + lane * 8);

    int bb = r0b >> 11;            // batch
    int h  = c0 >> 7;              // head
    int bhw = bb * 16 + h;
    int tile16 = (r0b & 2047) >> 4;   // 16-row tile index within bh
    int kbt = (r0b & 2047) >> 6;      // 64-key tile index (for Vf)
    floatx4 zero4 = {0.f, 0.f, 0.f, 0.f};

    floatx4 acc[4] = {zero4, zero4, zero4, zero4};
#pragma unroll
    for (int kf = 0; kf < 4; kf++) {
#pragma unroll
        for (int nf = 0; nf < 4; nf++) {
            bf16x8 b = *(const bf16x8*)(Wf + (size_t)((cg4 + nf) * 4 + kf) * 512 + lane * 8);
            acc[nf] = MFMA32K(a[kf], b, acc[nf]);
        }
    }

    // stage (+bias, cast). z<2: [row][col]; z==2: [col][row]
#pragma unroll
    for (int nf = 0; nf < 4; nf++) {
        int col = nf * 16 + lrow;
        float bvv = bias[c0 + col];
#pragma unroll
        for (int r = 0; r < 4; r++) {
            int row = wave * 16 + quad * 4 + r;
            bf16 val = (bf16)(acc[nf][r] + bvv);
            if (z < 2) tile[row][col] = val;
            else       tile[col][row] = val;
        }
    }
    __syncthreads();

    if (z < 2) {
        // Q and K share the same fragment-major layout
        bf16* dst = (z == 0) ? Qf : Kf;
        int s = wave;                              // 16-row tile 0..3
        int kfbase = (c0 & 127) >> 5;              // 0 or 2
        size_t fbase = ((size_t)bhw * 128 + tile16 + s) * 4 + kfbase;
#pragma unroll
        for (int kfl = 0; kfl < 2; kfl++) {
            bf16x8 w = *(const bf16x8*)(&tile[s * 16 + lrow][kfl * 32 + quad * 8]);
            *(bf16x8*)(dst + (fbase + kfl) * 512 + lane * 8) = w;
        }
    } else {
        int nfl = wave;
        int nfbase = (c0 & 127) >> 4;              // 0 or 4
        size_t fbase = (((size_t)bhw * 32 + kbt) * 8 + (nfbase + nfl)) * 2;
#pragma unroll
        for (int g = 0; g < 2; g++) {
            bf16x4 a0 = *(const bf16x4*)(&tile[nfl * 16 + lrow][g * 32 + quad * 4]);
            bf16x4 a1 = *(const bf16x4*)(&tile[nfl * 16 + lrow][g * 32 + 16 + quad * 4]);
            bf16x8 w;
            w[0]=a0[0]; w[1]=a0[1]; w[2]=a0[2]; w[3]=a0[3];
            w[4]=a1[0]; w[5]=a1[1]; w[6]=a1[2]; w[7]=a1[3];
            *(bf16x8*)(Vf + (fbase + g) * 512 + lane * 8) = w;
        }
    }
}

// ---------------------------------------------------------------------------
// Kernel B: flash attention — R11 frozen structure + mbias staged in LDS
// (R13 concept, with the per-lane global address FIXED: + lane*8).
// Moves the per-iter mask loads out of the vmcnt(0)-drained window into the
// lgkmcnt domain. LDS 72KB; occupancy unchanged (grid 512 = 2 blocks/CU).
// ---------------------------------------------------------------------------
__global__ __launch_bounds__(256) void flash_attn(const bf16* __restrict__ Qf,
                                                  const bf16* __restrict__ Kf,
                                                  const bf16* __restrict__ Vf,
                                                  const float* __restrict__ mbias,
                                                  const int* __restrict__ mask,
                                                  bf16* __restrict__ ctxf) {
    __shared__ bf16 sm[36864];   // [0,32768): K/V dbuf; [32768,36864): mbias row (2048 f32)
    float* mbL = (float*)&sm[32768];

    int tid = threadIdx.x;
    int wave = tid >> 6, lane = tid & 63;
    int lrow = lane & 15, quad = lane >> 4;
    // XCD swizzle: 512 blocks = 8 xcd * (4 bh * 16 qblk)
    int bid = blockIdx.x;
    int xcd = bid & 7, seq = bid >> 3;          // seq 0..63
    int bh  = xcd * 4 + (seq >> 4);             // 0..31
    int qblk = seq & 15;                        // 0..15
    int b  = bh >> 4;
    int q0 = qblk * 128 + wave * 32;

    const float* mbp = mbias + b * N_;
    const bf16* kbase = Kf + (size_t)bh * 32 * 8192;
    const bf16* vbase = Vf + (size_t)bh * 32 * 8192;

    // Q B-frags from Qf (coalesced 16B loads), held all loop
    bf16x8 qf[2][4];
#pragma unroll
    for (int u = 0; u < 2; u++)
#pragma unroll
        for (int kf = 0; kf < 4; kf++)
            qf[u][kf] = *(const bf16x8*)(Qf + (size_t)(((size_t)bh * 128 + (q0 >> 4) + u) * 4 + kf) * 512 + lane * 8);

    bf16x8 ones;
#pragma unroll
    for (int j = 0; j < 8; j++) ones[j] = (bf16)1.0f;

    floatx4 zero4 = {0.f, 0.f, 0.f, 0.f};
    floatx4 O[2][8];
#pragma unroll
    for (int u = 0; u < 2; u++)
#pragma unroll
        for (int nf = 0; nf < 8; nf++) O[u][nf] = zero4;
    floatx4 Oext[2] = {zero4, zero4};   // row sums l[q] via ones-MFMA

    const float scale = 0.0883883476483184f;   // 1/sqrt(128)

    // ---- prologue: DMA tile 0 into buffer 0 + mbias row into LDS ----
#pragma unroll
    for (int i = 0; i < 4; i++) {
        int seg = wave * 4 + i;                // 0..15, 1KB each
        load_lds16(kbase + seg * 512 + lane * 8, &sm[seg * 512]);
        load_lds16(vbase + seg * 512 + lane * 8, &sm[8192 + seg * 512]);
    }
#pragma unroll
    for (int i = 0; i < 2; i++) {
        int seg = wave * 2 + i;                // 0..7, 256 floats (1KB) each
        load_lds16((const bf16*)(mbp + seg * 256) + lane * 8, (bf16*)(mbL + seg * 256));
    }

    for (int kb = 0; kb < 32; kb++) {
        int cur = (kb & 1) << 14;              // 0 or 16384

        // ---- 1./2. wait my DMA(kb) (+prologue mbias on kb==0), barrier ----
        __builtin_amdgcn_s_waitcnt(WAITCNT_VM(0));
        __builtin_amdgcn_s_barrier();

        // ---- 3. prefetch DMA(kb+1) into the other buffer ----
        if (kb < 31) {
            int nxt = cur ^ 16384;
            const bf16* ksrc = kbase + (size_t)(kb + 1) * 8192;
            const bf16* vsrc = vbase + (size_t)(kb + 1) * 8192;
#pragma unroll
            for (int i = 0; i < 4; i++) {
                int seg = wave * 4 + i;
                load_lds16(ksrc + seg * 512 + lane * 8, &sm[nxt + seg * 512]);
                load_lds16(vsrc + seg * 512 + lane * 8, &sm[nxt + 8192 + seg * 512]);
            }
        }

        // ---- 4. S^T per 16-key tile; exp; pack into K=32 B-frags ----
        bf16x8 pf[2][2];
#pragma unroll
        for (int s = 0; s < 4; s++) {
            floatx4 S0 = zero4, S1 = zero4;
#pragma unroll
            for (int kf = 0; kf < 4; kf++) {
                bf16x8 kfr = *(const bf16x8*)(&sm[cur + ((s * 4 + kf) * 64 + lane) * 8]);
                S0 = MFMA32K(kfr, qf[0][kf], S0);
                S1 = MFMA32K(kfr, qf[1][kf], S1);
            }
            float4 mb4 = *(const float4*)(mbL + kb * 64 + s * 16 + quad * 4);  // LDS (lgkmcnt)
            const float* mbr = (const float*)&mb4;
            int g = s >> 1, o = (s & 1) * 4;
#pragma unroll
            for (int r = 0; r < 4; r++) {
                float p0 = __expf(fmaf(S0[r], scale, mbr[r]));
                float p1 = __expf(fmaf(S1[r], scale, mbr[r]));
                pf[0][g][o + r] = (bf16)p0;
                pf[1][g][o + r] = (bf16)p1;
            }
        }

        // ---- l row-sums via ones-MFMA ----
#pragma unroll
        for (int g = 0; g < 2; g++) {
            Oext[0] = MFMA32K(ones, pf[0][g], Oext[0]);
            Oext[1] = MFMA32K(ones, pf[1][g], Oext[1]);
        }

        // ---- PV: O^T[d][q] += V^T P, full-rate K=32 ----
#pragma unroll
        for (int nf = 0; nf < 8; nf++) {
#pragma unroll
            for (int g = 0; g < 2; g++) {
                bf16x8 vfr = *(const bf16x8*)(&sm[cur + 8192 + ((nf * 2 + g) * 64 + lane) * 8]);
                O[0][nf] = MFMA32K(vfr, pf[0][g], O[0][nf]);
                O[1][nf] = MFMA32K(vfr, pf[1][g], O[1][nf]);
            }
        }
        // no end-of-iter barrier: next iter's barrier (after vmcnt) protects
        // buf[nxt] — every wave reaching it has finished this iter's reads
    }

    // ---- epilogue: normalize, query-mask, reshape via LDS -> ctxf frags ----
    __syncthreads();                    // full drain before reusing sm
    const int* mp = mask + b * N_;
    int wb = wave * 4352;               // 32 rows * 136 stride per wave ([0,17408))
#pragma unroll
    for (int u = 0; u < 2; u++) {
        float lsum = Oext[u][0];
        int q = q0 + u * 16 + lrow;
        float rl = (mp[q] && lsum > 0.f) ? (1.0f / lsum) : 0.f;
#pragma unroll
        for (int nf = 0; nf < 8; nf++) {
            bf16x4 o;
#pragma unroll
            for (int j = 0; j < 4; j++) o[j] = (bf16)(O[u][nf][j] * rl);
            *(bf16x4*)(&sm[wb + (u * 16 + lrow) * 136 + nf * 16 + quad * 4]) = o;
        }
    }
    __syncthreads();
    int h4 = (bh & 15) * 4;
    size_t qtb = (size_t)b * 128 + (q0 >> 4);
#pragma unroll
    for (int u = 0; u < 2; u++) {
#pragma unroll
        for (int kfl = 0; kfl < 4; kfl++) {
            bf16x8 w = *(const bf16x8*)(&sm[wb + (u * 16 + lrow) * 136 + kfl * 32 + quad * 8]);
            *(bf16x8*)(ctxf + ((qtb + u) * 64 + h4 + kfl) * 512 + lane * 8) = w;
        }
    }
}

// ---------------------------------------------------------------------------
// Kernel C: out = ctx @ Wo + bo, fp32 out. SPLIT-K x2: 2 waves/block, wave w
// accumulates kf-half w, LDS-combine, wave 0 stores. Deterministic.
// ---------------------------------------------------------------------------
__global__ __launch_bounds__(128) void out_proj(const bf16* __restrict__ ctxf,
                                                const bf16* __restrict__ Wof,
                                                const float* __restrict__ bo,
                                                float* __restrict__ out) {
    __shared__ float red[512];         // wave1 partials: [nf2][r4][lane64]
    int tid = threadIdx.x;
    int wave = tid >> 6, lane = tid & 63;
    int lrow = lane & 15, quad = lane >> 4;
    int qt = blockIdx.x;               // 16-row tile
    int ct = blockIdx.y * 2;           // two 16-col tiles
    int r0 = qt * 16, c0 = ct * 16;

    floatx4 zero4 = {0.f, 0.f, 0.f, 0.f};
    floatx4 acc[2] = {zero4, zero4};
    const bf16* ap = ctxf + ((size_t)qt * 64 + wave * 32) * 512 + lane * 8;
    const bf16* b0 = Wof + ((size_t)ct * 64 + wave * 32) * 512 + lane * 8;
    const bf16* b1 = b0 + (size_t)64 * 512;
#pragma unroll 4
    for (int kf = 0; kf < 32; kf++) {
        bf16x8 a  = *(const bf16x8*)(ap + (size_t)kf * 512);
        bf16x8 w0 = *(const bf16x8*)(b0 + (size_t)kf * 512);
        bf16x8 w1 = *(const bf16x8*)(b1 + (size_t)kf * 512);
        acc[0] = MFMA32K(a, w0, acc[0]);
        acc[1] = MFMA32K(a, w1, acc[1]);
    }
    if (wave == 1) {
#pragma unroll
        for (int nf = 0; nf < 2; nf++)
#pragma unroll
            for (int r = 0; r < 4; r++)
                red[nf * 256 + r * 64 + lane] = acc[nf][r];
    }
    __syncthreads();
    if (wave == 0) {
#pragma unroll
        for (int nf = 0; nf < 2; nf++) {
            int col = c0 + nf * 16 + lrow;
            float bv = bo[col];
#pragma unroll
            for (int r = 0; r < 4; r++) {
                int m = r0 + quad * 4 + r;
                out[(size_t)m * 128 + col] = acc[nf][r] + red[nf * 256 + r * 64 + lane] + bv;
            }
        }
    }
}

// ---------------------------------------------------------------------------
extern "C" void kernel_launch(void* const* d_in, const int* in_sizes, int n_in,
                              void* d_out, int out_size, void* d_ws, size_t ws_size,
                              hipStream_t stream) {
    const float* x    = (const float*)d_in[0];
    const int*   mask = (const int*)d_in[1];
    const float* Wq   = (const float*)d_in[2];
    const float* bq   = (const float*)d_in[3];
    const float* Wk   = (const float*)d_in[4];
    const float* bk   = (const float*)d_in[5];
    const float* Wv   = (const float*)d_in[6];
    const float* bv   = (const float*)d_in[7];
    const float* Wo   = (const float*)d_in[8];
    const float* bo   = (const float*)d_in[9];
    float* out = (float*)d_out;

    char* ws = (char*)d_ws;
    size_t off = 0;
    bf16* Wqf = (bf16*)(ws + off); off += (size_t)262144 * 2;
    bf16* Wkf = (bf16*)(ws + off); off += (size_t)262144 * 2;
    bf16* Wvf = (bf16*)(ws + off); off += (size_t)262144 * 2;
    bf16* Wof = (bf16*)(ws + off); off += (size_t)262144 * 2;
    bf16* xf  = (bf16*)(ws + off); off += (size_t)524288 * 2;
    size_t qkv_elems = (size_t)BH_ * N_ * 128;           // 8.4M
    bf16* Qf  = (bf16*)(ws + off); off += qkv_elems * 2; // fragment-major
    bf16* Kf  = (bf16*)(ws + off); off += qkv_elems * 2; // fragment-major
    bf16* Vf  = (bf16*)(ws + off); off += qkv_elems * 2; // fragment-major
    bf16* ctxf = (bf16*)(ws + off); off += (size_t)M_ * ALL_ * 2;
    float* mbias = (float*)(ws + off); off += (size_t)B_ * N_ * 4;
    (void)ws_size; (void)in_sizes; (void)n_in; (void)out_size;

    prep_weights<<<192, 256, 0, stream>>>(x, Wq, Wk, Wv, Wo, mask,
                                          Wqf, Wkf, Wvf, Wof, xf, mbias);

    qkv_proj<<<dim3(64, 32, 3), 256, 0, stream>>>(xf, bq, bk, bv, Wqf, Wkf, Wvf,
                                                  Qf, Kf, Vf);

    flash_attn<<<512, 256, 0, stream>>>(Qf, Kf, Vf, mbias, mask, ctxf);

    out_proj<<<dim3(256, 4), 128, 0, stream>>>(ctxf, Wof, bo, out);
}